// Round 1
// 403.003 us; speedup vs baseline: 1.3555x; 1.3555x over previous
//
#include <hip/hip_runtime.h>

#define B_    32
#define NW_   64
#define BW_   2048   // B*NW
#define L_    49
#define D_    192
#define PROJ_ 256
#define H_    8
#define HD_   32

typedef __attribute__((ext_vector_type(8))) short bf16x8;
typedef __attribute__((ext_vector_type(4))) float f32x4;

// ---------------------------------------------------------------------------
// Dynamic LDS layout (123904 B total):
//   [0,      25600)  Xb  : staged input bf16 [64][200] (pitch 200 -> 2-way banks)
//   [25600,  91136)  QKP : per-head 8192 B. [0,4096)=q (later Ob), [4096,8192)=k.
//                          P[64][64] bf16 overlays the full 8 KB after QK^T.
//   [91136, 123904)  VT  : per-head 4096 B: V^T [32 c][64 kk] bf16, XOR-swizzled.
// Swizzles (keyed on the ROW of the element, applied to byte offset):
//   [64][32] regions (q/k/Ob): byte ^= ((row>>1)&3)<<4   (chunk bits 4-5)
//   [..][64] regions (P/VT)  : byte ^= (row&7)<<4        (chunk bits 4-6)
// ---------------------------------------------------------------------------
#define XB_OFF    0
#define QKP_OFF   25600
#define VT_OFF    91136
#define LDS_BYTES 123904

__device__ __forceinline__ short f2bf(float f) {
    union { float f; unsigned u; } v; v.f = f;
    unsigned r = v.u + 0x7FFFu + ((v.u >> 16) & 1u);   // RNE
    return (short)(r >> 16);
}

// ---------------------------------------------------------------------------
// Weight prep (unchanged): Wt[n][k] bf16 (k contiguous) = W[k][n].
// grid (256, 4), block 256. y=0..2: Wq/Wk/Wv (192x256 -> 256x192). y=3: Ww.
// ---------------------------------------------------------------------------
__global__ __launch_bounds__(256) void prep_weights(
    const float* __restrict__ Wq, const float* __restrict__ Wk,
    const float* __restrict__ Wv, const float* __restrict__ Ww,
    short* __restrict__ Wqt, short* __restrict__ Wkt,
    short* __restrict__ Wvt, short* __restrict__ Wwt)
{
    const int sel = blockIdx.y;
    const int n   = blockIdx.x;
    const int tid = threadIdx.x;
    if (sel < 3) {
        const float* src = (sel == 0) ? Wq : (sel == 1) ? Wk : Wv;
        short* dst = (sel == 0) ? Wqt : (sel == 1) ? Wkt : Wvt;
        if (tid < D_) dst[n * D_ + tid] = f2bf(src[tid * PROJ_ + n]);
    } else {
        if (n < D_) Wwt[n * PROJ_ + tid] = f2bf(Ww[tid * D_ + n]);
    }
}

// ---------------------------------------------------------------------------
// Mask prep: mbits[w][q] = 64-bit row bitmask, bit j = (mask[w][q][j] != 0).
// Rows q>=49 -> 0. One wave per (w, 16 q-rows) via __ballot. grid 64 x 256.
// ---------------------------------------------------------------------------
__global__ __launch_bounds__(256) void prep_mask(
    const int* __restrict__ mask, unsigned long long* __restrict__ mbits)
{
    const int w    = blockIdx.x;
    const int wave = threadIdx.x >> 6;
    const int lane = threadIdx.x & 63;
    for (int qq = 0; qq < 16; ++qq) {
        const int q = wave * 16 + qq;
        int val = 0;
        if (q < L_ && lane < L_) val = mask[w * (L_ * L_) + q * L_ + lane];
        unsigned long long bits = __ballot(val != 0);
        if (lane == 0) mbits[w * 64 + q] = bits;
    }
}

// ---------------------------------------------------------------------------
// Fully fused: QKV proj -> swapped QK^T -> softmax -> PV (O^T) -> out-proj.
// One block per window, 512 threads = 8 waves; wave w == head w for proj cols
// 32w..32w+31, so q/k/vT/P are wave-private (no barriers inside attention).
// ---------------------------------------------------------------------------
__global__ __launch_bounds__(512) void fused_kernel(
    const float* __restrict__ query, const float* __restrict__ key_,
    const float* __restrict__ value,
    const short* __restrict__ Wqt, const short* __restrict__ Wkt,
    const short* __restrict__ Wvt,
    const float* __restrict__ bq, const float* __restrict__ bk,
    const unsigned long long* __restrict__ mbits,
    const short* __restrict__ Wwt, const float* __restrict__ bwb,
    float* __restrict__ out)
{
    extern __shared__ char lds[];
    short* Xb = (short*)(lds + XB_OFF);

    const int bw   = blockIdx.x;
    const int w    = bw & (NW_ - 1);
    const int tid  = threadIdx.x;
    const int wave = tid >> 6;          // == head
    const int lane = tid & 63;
    const int m16  = lane & 15;
    const int quad = lane >> 4;

    const int swz2 = ((m16 >> 1) & 3) << 4;   // read-side swizzle, [64][32] regions
    const int swz3 = (m16 & 7) << 4;          // read/write swizzle, [..][64] regions

    char* myQKP = lds + QKP_OFF + wave * 8192;
    char* myVT  = lds + VT_OFF  + wave * 4096;

    // ---------------- QKV projection ----------------
    #pragma unroll
    for (int sel = 0; sel < 3; ++sel) {
        const float* x  = (sel == 0) ? query : (sel == 1) ? key_ : value;
        const short* Wt = (sel == 0) ? Wqt : (sel == 1) ? Wkt : Wvt;

        __syncthreads();   // previous users of Xb done
        #pragma unroll
        for (int it = 0; it < 6; ++it) {
            const int i = tid + it * 512;            // 0..3071
            const int l = i / 48, c4 = i - l * 48;
            short4 s4 = {0, 0, 0, 0};
            if (l < L_) {
                float4 v = *(const float4*)&x[((size_t)bw * L_ + l) * D_ + c4 * 4];
                s4.x = f2bf(v.x); s4.y = f2bf(v.y); s4.z = f2bf(v.z); s4.w = f2bf(v.w);
            }
            *(short4*)&Xb[l * 200 + c4 * 4] = s4;
        }
        __syncthreads();

        f32x4 acc[4][2];
        #pragma unroll
        for (int mt = 0; mt < 4; ++mt)
            #pragma unroll
            for (int nt = 0; nt < 2; ++nt)
                acc[mt][nt] = (f32x4){0.f, 0.f, 0.f, 0.f};

        #pragma unroll
        for (int kc = 0; kc < 6; ++kc) {
            bf16x8 af[4], bf[2];
            #pragma unroll
            for (int mt = 0; mt < 4; ++mt)
                af[mt] = *(const bf16x8*)&Xb[(mt * 16 + m16) * 200 + kc * 32 + quad * 8];
            #pragma unroll
            for (int nt = 0; nt < 2; ++nt)
                bf[nt] = *(const bf16x8*)&Wt[(size_t)(wave * 32 + nt * 16 + m16) * D_ + kc * 32 + quad * 8];
            #pragma unroll
            for (int mt = 0; mt < 4; ++mt)
                #pragma unroll
                for (int nt = 0; nt < 2; ++nt)
                    acc[mt][nt] = __builtin_amdgcn_mfma_f32_16x16x32_bf16(
                        af[mt], bf[nt], acc[mt][nt], 0, 0, 0);
        }

        if (sel < 2) {
            // q/k: row-major [l:64][c:32] per head, swizzled; 2-byte scatter into LDS
            char* dstb = myQKP + sel * 4096;
            #pragma unroll
            for (int nt = 0; nt < 2; ++nt) {
                const int c = nt * 16 + m16;
                const float bias = ((sel == 0) ? bq : bk)[wave * 32 + c];
                #pragma unroll
                for (int mt = 0; mt < 4; ++mt)
                    #pragma unroll
                    for (int r = 0; r < 4; ++r) {
                        const int i = mt * 16 + quad * 4 + r;
                        *(short*)(dstb + i * 64 + ((2 * c) ^ (((i >> 1) & 3) << 4))) =
                            f2bf(acc[mt][nt][r] + bias);
                    }
            }
        } else {
            // vT: [c:32][kk:64] per head; r=0..3 contiguous -> packed b64 writes
            #pragma unroll
            for (int nt = 0; nt < 2; ++nt) {
                const int c = nt * 16 + m16;
                #pragma unroll
                for (int mt = 0; mt < 4; ++mt) {
                    short4 o4;
                    o4.x = f2bf(acc[mt][nt][0]); o4.y = f2bf(acc[mt][nt][1]);
                    o4.z = f2bf(acc[mt][nt][2]); o4.w = f2bf(acc[mt][nt][3]);
                    *(short4*)(myVT + c * 128 + ((mt * 32 + quad * 8) ^ swz3)) = o4;
                }
            }
        }
    }

    // ---------------- attention (wave-private, head = wave) ----------------
    unsigned long long mb[4];
    #pragma unroll
    for (int nt = 0; nt < 4; ++nt) mb[nt] = mbits[w * 64 + nt * 16 + m16];

    const float scale = 0.17677669529663687f;  // 1/sqrt(32)

    // S^T = K @ Q^T : lane holds S[q=16nt+m16][k=16mt+4quad+r]
    f32x4 sacc[4][4];
    #pragma unroll
    for (int mt = 0; mt < 4; ++mt)
        #pragma unroll
        for (int nt = 0; nt < 4; ++nt)
            sacc[mt][nt] = (f32x4){0.f, 0.f, 0.f, 0.f};
    {
        bf16x8 kf[4], qf[4];
        #pragma unroll
        for (int mt = 0; mt < 4; ++mt)
            kf[mt] = *(const bf16x8*)(myQKP + 4096 + (mt * 16 + m16) * 64 + ((quad * 16) ^ swz2));
        #pragma unroll
        for (int nt = 0; nt < 4; ++nt)
            qf[nt] = *(const bf16x8*)(myQKP + (nt * 16 + m16) * 64 + ((quad * 16) ^ swz2));
        #pragma unroll
        for (int mt = 0; mt < 4; ++mt)
            #pragma unroll
            for (int nt = 0; nt < 4; ++nt)
                sacc[mt][nt] = __builtin_amdgcn_mfma_f32_16x16x32_bf16(
                    kf[mt], qf[nt], sacc[mt][nt], 0, 0, 0);
    }

    // softmax per q-row: in-lane over 16 k-values + 2 quad-group shuffles;
    // P (bf16, normalized) packed b64 into the q+k region (both dead now)
    #pragma unroll
    for (int nt = 0; nt < 4; ++nt) {
        float e[4][4];
        float mx = -1e30f;
        #pragma unroll
        for (int mt = 0; mt < 4; ++mt)
            #pragma unroll
            for (int r = 0; r < 4; ++r) {
                const int k = mt * 16 + quad * 4 + r;
                float v = sacc[mt][nt][r] * scale;
                if (k >= L_) v = -INFINITY;                 // pad cols excluded exactly
                else if ((mb[nt] >> k) & 1ull) v = -1000.0f; // ref semantics
                e[mt][r] = v;
                mx = fmaxf(mx, v);
            }
        mx = fmaxf(mx, __shfl_xor(mx, 16, 64));
        mx = fmaxf(mx, __shfl_xor(mx, 32, 64));
        float sum = 0.f;
        #pragma unroll
        for (int mt = 0; mt < 4; ++mt)
            #pragma unroll
            for (int r = 0; r < 4; ++r) {
                const float ev = __expf(e[mt][r] - mx);
                e[mt][r] = ev;
                sum += ev;
            }
        sum += __shfl_xor(sum, 16, 64);
        sum += __shfl_xor(sum, 32, 64);
        const float inv = 1.0f / sum;
        const int prow = nt * 16 + m16;
        #pragma unroll
        for (int mt = 0; mt < 4; ++mt) {
            short4 p4;
            p4.x = f2bf(e[mt][0] * inv); p4.y = f2bf(e[mt][1] * inv);
            p4.z = f2bf(e[mt][2] * inv); p4.w = f2bf(e[mt][3] * inv);
            *(short4*)(myQKP + prow * 128 + ((mt * 32 + quad * 8) ^ swz3)) = p4;
        }
    }

    // O^T = V^T @ P^T : A from VT, B straight from P rows; K=64 (2 chunks)
    f32x4 oacc[2][4];
    #pragma unroll
    for (int mt2 = 0; mt2 < 2; ++mt2)
        #pragma unroll
        for (int nt = 0; nt < 4; ++nt)
            oacc[mt2][nt] = (f32x4){0.f, 0.f, 0.f, 0.f};
    #pragma unroll
    for (int kc = 0; kc < 2; ++kc) {
        bf16x8 vf[2], pf[4];
        #pragma unroll
        for (int mt2 = 0; mt2 < 2; ++mt2)
            vf[mt2] = *(const bf16x8*)(myVT + (mt2 * 16 + m16) * 128 + ((kc * 64 + quad * 16) ^ swz3));
        #pragma unroll
        for (int nt = 0; nt < 4; ++nt)
            pf[nt] = *(const bf16x8*)(myQKP + (nt * 16 + m16) * 128 + ((kc * 64 + quad * 16) ^ swz3));
        #pragma unroll
        for (int mt2 = 0; mt2 < 2; ++mt2)
            #pragma unroll
            for (int nt = 0; nt < 4; ++nt)
                oacc[mt2][nt] = __builtin_amdgcn_mfma_f32_16x16x32_bf16(
                    vf[mt2], pf[nt], oacc[mt2][nt], 0, 0, 0);
    }

    // O written A-layout-ready into the q-half ([64][32], swizzled), b64 packed
    #pragma unroll
    for (int nt = 0; nt < 4; ++nt) {
        const int prow = nt * 16 + m16;
        #pragma unroll
        for (int mt2 = 0; mt2 < 2; ++mt2) {
            short4 o4;
            o4.x = f2bf(oacc[mt2][nt][0]); o4.y = f2bf(oacc[mt2][nt][1]);
            o4.z = f2bf(oacc[mt2][nt][2]); o4.w = f2bf(oacc[mt2][nt][3]);
            *(short4*)(myQKP + prow * 64 + ((mt2 * 32 + quad * 8) ^ ((prow >> 1 & 3) << 4))) = o4;
        }
    }

    __syncthreads();   // all heads' O ready

    // ---------------- out-proj: out = O @ Ww + bw, K=256 ----------------
    // 12 col-tiles over 8 waves: wave w does tile w, and tile w+8 if w<4
    f32x4 cacc[4][2];
    #pragma unroll
    for (int mt = 0; mt < 4; ++mt)
        #pragma unroll
        for (int nt = 0; nt < 2; ++nt)
            cacc[mt][nt] = (f32x4){0.f, 0.f, 0.f, 0.f};
    const int ntN = (wave < 4) ? 2 : 1;
    #pragma unroll
    for (int kc = 0; kc < 8; ++kc) {
        bf16x8 af[4], bfw[2];
        #pragma unroll
        for (int mt = 0; mt < 4; ++mt)
            af[mt] = *(const bf16x8*)(lds + QKP_OFF + kc * 8192 + (mt * 16 + m16) * 64 + ((quad * 16) ^ swz2));
        #pragma unroll
        for (int nt = 0; nt < 2; ++nt)
            if (nt < ntN) {
                const int tile = wave + nt * 8;
                bfw[nt] = *(const bf16x8*)&Wwt[(size_t)(tile * 16 + m16) * PROJ_ + kc * 32 + quad * 8];
            }
        #pragma unroll
        for (int mt = 0; mt < 4; ++mt)
            #pragma unroll
            for (int nt = 0; nt < 2; ++nt)
                if (nt < ntN)
                    cacc[mt][nt] = __builtin_amdgcn_mfma_f32_16x16x32_bf16(
                        af[mt], bfw[nt], cacc[mt][nt], 0, 0, 0);
    }
    #pragma unroll
    for (int nt = 0; nt < 2; ++nt) {
        if (nt < ntN) {
            const int col = (wave + nt * 8) * 16 + m16;
            const float bias = bwb[col];
            #pragma unroll
            for (int mt = 0; mt < 4; ++mt)
                #pragma unroll
                for (int r = 0; r < 4; ++r) {
                    const int i = mt * 16 + quad * 4 + r;
                    if (i < L_)
                        out[((size_t)bw * L_ + i) * D_ + col] = cacc[mt][nt][r] + bias;
                }
        }
    }
}

extern "C" void kernel_launch(void* const* d_in, const int* in_sizes, int n_in,
                              void* d_out, int out_size, void* d_ws, size_t ws_size,
                              hipStream_t stream) {
    const float* query = (const float*)d_in[0];
    const float* key_  = (const float*)d_in[1];
    const float* value = (const float*)d_in[2];
    const int*   mask  = (const int*)d_in[3];
    const float* Wq    = (const float*)d_in[4];
    const float* bq    = (const float*)d_in[5];
    const float* Wk    = (const float*)d_in[6];
    const float* bk    = (const float*)d_in[7];
    const float* Wv    = (const float*)d_in[8];
    const float* Ww    = (const float*)d_in[9];
    const float* bw    = (const float*)d_in[10];
    float* out = (float*)d_out;

    unsigned long long* mbits = (unsigned long long*)d_ws;     // 64*64 u64 = 32 KB
    short* Wqt = (short*)(mbits + 64 * 64);
    short* Wkt = Wqt + PROJ_ * D_;
    short* Wvt = Wkt + PROJ_ * D_;
    short* Wwt = Wvt + PROJ_ * D_;

    static bool attr_set = false;
    if (!attr_set) {
        (void)hipFuncSetAttribute(reinterpret_cast<const void*>(fused_kernel),
                                  hipFuncAttributeMaxDynamicSharedMemorySize, LDS_BYTES);
        attr_set = true;
    }

    prep_weights<<<dim3(256, 4), 256, 0, stream>>>(Wq, Wk, Wv, Ww, Wqt, Wkt, Wvt, Wwt);
    prep_mask<<<dim3(64), 256, 0, stream>>>(mask, mbits);
    fused_kernel<<<dim3(BW_), 512, LDS_BYTES, stream>>>(
        query, key_, value, Wqt, Wkt, Wvt, bq, bk, mbits, Wwt, bw, out);
}

// Round 2
// 366.954 us; speedup vs baseline: 1.4887x; 1.0982x over previous
//
#include <hip/hip_runtime.h>

#define B_    32
#define NW_   64
#define BW_   2048   // B*NW
#define L_    49
#define D_    192
#define PROJ_ 256
#define H_    8
#define HD_   32

typedef __attribute__((ext_vector_type(8))) short bf16x8;
typedef __attribute__((ext_vector_type(4))) float f32x4;

// ---------------------------------------------------------------------------
// Dynamic LDS layout (78848 B -> 2 blocks/CU):
//   [0,     24576)  Xb: staged input bf16, row l at l*384, byte ^= (l&7)<<4.
//                   After sel2 frag reads (barrier), overlaid by per-WAVE
//                   V^T slots: slot w at w*4096, [c:32][kk:64] bf16,
//                   byte ^= (c&7)<<4.
//   [24576, 74752)  per-head 6272 B (8 heads):
//                     proj:  q rows [49][32] at +0, k at +3136; row i 64 B,
//                            byte ^= ((i>>1)&3)<<4
//                     attn:  P rows [49][64] overlays q+k; row q 128 B,
//                            byte ^= (q&7)<<4
//                     out:   O rows [49][32] overlays P; same swizzle as q/k
//   [74752, 78848)  tail pad: keeps deliberate pad-row OOB reads in-allocation
// ---------------------------------------------------------------------------
#define QK_OFF    24576
#define LDS_BYTES 78848

__device__ __forceinline__ short f2bf(float f) {
    union { float f; unsigned u; } v; v.f = f;
    unsigned r = v.u + 0x7FFFu + ((v.u >> 16) & 1u);   // RNE
    return (short)(r >> 16);
}

// packed f32x2 -> bf16x2 (RNE, bit-identical to f2bf for finite values)
__device__ __forceinline__ unsigned cvtpk(float lo, float hi) {
    unsigned r;
    asm("v_cvt_pk_bf16_f32 %0, %1, %2" : "=v"(r) : "v"(lo), "v"(hi));
    return r;
}

// ---------------------------------------------------------------------------
// Single prep dispatch: weight transposes (bf16) + mask row-bitmasks.
// grid 1216 x 256:
//   b<768 : Wq/Wk/Wv (192x256 -> Wt[n][k], k contiguous)
//   b<960 : Ww (256x192 -> Wwt[n][k])
//   else  : mbits[w][q] via __ballot, 256 blocks (4 rows/wave)
// ---------------------------------------------------------------------------
__global__ __launch_bounds__(256) void prep_kernel(
    const float* __restrict__ Wq, const float* __restrict__ Wk,
    const float* __restrict__ Wv, const float* __restrict__ Ww,
    const int* __restrict__ mask,
    short* __restrict__ Wqt, short* __restrict__ Wkt,
    short* __restrict__ Wvt, short* __restrict__ Wwt,
    unsigned long long* __restrict__ mbits)
{
    const int b   = blockIdx.x;
    const int tid = threadIdx.x;
    if (b < 768) {
        const int sel = b >> 8, n = b & 255;
        const float* src = (sel == 0) ? Wq : (sel == 1) ? Wk : Wv;
        short* dst = (sel == 0) ? Wqt : (sel == 1) ? Wkt : Wvt;
        if (tid < D_) dst[n * D_ + tid] = f2bf(src[tid * PROJ_ + n]);
    } else if (b < 960) {
        const int n = b - 768;                    // 0..191
        Wwt[n * PROJ_ + tid] = f2bf(Ww[tid * D_ + n]);
    } else {
        const int m = b - 960;                    // 0..255
        const int w = m >> 2, chunk = m & 3;
        const int wave = tid >> 6, lane = tid & 63;
        #pragma unroll
        for (int k = 0; k < 4; ++k) {
            const int q = chunk * 16 + wave * 4 + k;   // 0..63
            int val = 0;
            if (q < L_ && lane < L_) val = mask[w * (L_ * L_) + q * L_ + lane];
            unsigned long long bits = __ballot(val != 0);
            if (lane == 0) mbits[w * 64 + q] = bits;
        }
    }
}

// ---------------------------------------------------------------------------
// Fully fused window attention: QKV proj -> swapped QK^T -> softmax -> PV ->
// out-proj. One block per window, 256 threads = 4 waves, 2 heads/wave.
// LDS 78848 B -> 2 blocks/CU (decorrelated barrier domains).
// ---------------------------------------------------------------------------
__global__ __launch_bounds__(256, 2) void fused_kernel(
    const float* __restrict__ query, const float* __restrict__ key_,
    const float* __restrict__ value,
    const short* __restrict__ Wqt, const short* __restrict__ Wkt,
    const short* __restrict__ Wvt,
    const float* __restrict__ bq, const float* __restrict__ bk,
    const unsigned long long* __restrict__ mbits,
    const short* __restrict__ Wwt, const float* __restrict__ bwb,
    float* __restrict__ out)
{
    extern __shared__ char lds[];

    const int bw   = blockIdx.x;
    const int w    = bw & (NW_ - 1);
    const int tid  = threadIdx.x;
    const int wave = tid >> 6;
    const int lane = tid & 63;
    const int m16  = lane & 15;
    const int quad = lane >> 4;

    const int swz2 = ((m16 >> 1) & 3) << 4;   // [49][32] regions (q/k/O)
    const int swz3 = (m16 & 7) << 4;          // [..][64] regions (Xb/P/VT)

    char* qkR  = lds + QK_OFF;
    char* slot = lds + wave * 4096;           // V^T slot (overlays Xb later)

    // prefetch mask bitmasks (L2) under the staging phase
    unsigned long long mb[4];
    #pragma unroll
    for (int nt = 0; nt < 4; ++nt) mb[nt] = mbits[w * 64 + nt * 16 + m16];

    uint2 vpk[2][4];   // deferred V^T packs for head 2w+1

    // ---------------- QKV projection (2 heads per wave) ----------------
    #pragma unroll
    for (int sel = 0; sel < 3; ++sel) {
        const float* x  = (sel == 0) ? query : (sel == 1) ? key_ : value;
        const short* Wt = (sel == 0) ? Wqt : (sel == 1) ? Wkt : Wvt;

        __syncthreads();   // previous users of Xb done
        #pragma unroll
        for (int it = 0; it < 12; ++it) {
            const int i = tid + it * 256;            // 0..3071
            const int l = i / 48, c4 = i - l * 48;
            uint2 u = {0u, 0u};
            if (l < L_) {
                float4 v = *(const float4*)&x[((size_t)bw * L_ + l) * D_ + c4 * 4];
                u.x = cvtpk(v.x, v.y); u.y = cvtpk(v.z, v.w);
            }
            *(uint2*)(lds + l * 384 + ((c4 * 8) ^ ((l & 7) << 4))) = u;
        }
        __syncthreads();

        f32x4 acc[4][4];
        #pragma unroll
        for (int mt = 0; mt < 4; ++mt)
            #pragma unroll
            for (int nt = 0; nt < 4; ++nt)
                acc[mt][nt] = (f32x4){0.f, 0.f, 0.f, 0.f};

        #pragma unroll
        for (int kc = 0; kc < 6; ++kc) {
            bf16x8 af[4], bfr[4];
            #pragma unroll
            for (int mt = 0; mt < 4; ++mt)
                af[mt] = *(const bf16x8*)(lds + (mt * 16 + m16) * 384 +
                                          ((kc * 64 + quad * 16) ^ swz3));
            #pragma unroll
            for (int nt = 0; nt < 4; ++nt)
                bfr[nt] = *(const bf16x8*)&Wt[(size_t)(wave * 64 + nt * 16 + m16) * D_ +
                                              kc * 32 + quad * 8];
            __builtin_amdgcn_s_setprio(1);
            #pragma unroll
            for (int mt = 0; mt < 4; ++mt)
                #pragma unroll
                for (int nt = 0; nt < 4; ++nt)
                    acc[mt][nt] = __builtin_amdgcn_mfma_f32_16x16x32_bf16(
                        af[mt], bfr[nt], acc[mt][nt], 0, 0, 0);
            __builtin_amdgcn_s_setprio(0);
        }

        if (sel == 2) __syncthreads();   // all Xb reads done before V^T overlays it

        if (sel < 2) {
            // q/k: [49][32] per head, swizzled 2-byte scatter
            const float* bsel = (sel == 0) ? bq : bk;
            #pragma unroll
            for (int nt = 0; nt < 4; ++nt) {
                const int head = wave * 2 + (nt >> 1);
                const int c = (nt & 1) * 16 + m16;
                const float bias = bsel[wave * 64 + nt * 16 + m16];
                char* db = qkR + head * 6272 + sel * 3136;
                #pragma unroll
                for (int mt = 0; mt < 4; ++mt)
                    #pragma unroll
                    for (int r = 0; r < 4; ++r) {
                        const int i = mt * 16 + quad * 4 + r;
                        if (i < L_)
                            *(short*)(db + i * 64 + ((2 * c) ^ (((i >> 1) & 3) << 4))) =
                                f2bf(acc[mt][nt][r] + bias);
                    }
            }
        } else {
            // v: head 2w -> V^T slot now; head 2w+1 kept packed in registers
            #pragma unroll
            for (int nt = 0; nt < 4; ++nt) {
                const int c = (nt & 1) * 16 + m16;
                #pragma unroll
                for (int mt = 0; mt < 4; ++mt) {
                    uint2 p;
                    p.x = cvtpk(acc[mt][nt][0], acc[mt][nt][1]);
                    p.y = cvtpk(acc[mt][nt][2], acc[mt][nt][3]);
                    if (nt < 2)
                        *(uint2*)(slot + c * 128 + ((mt * 32 + quad * 8) ^ swz3)) = p;
                    else
                        vpk[nt - 2][mt] = p;
                }
            }
        }
    }

    // ---------------- attention (wave-private, heads 2w, 2w+1) ----------------
    const float scale = 0.17677669529663687f;  // 1/sqrt(32)

    #pragma unroll 1
    for (int hh = 0; hh < 2; ++hh) {
        const int head = wave * 2 + hh;
        char* qb = qkR + head * 6272;
        char* kb = qb + 3136;

        // S^T = K @ Q^T : lane holds S[q=16nt+m16][k=16mt+4quad+r]
        f32x4 sacc[4][4];
        #pragma unroll
        for (int mt = 0; mt < 4; ++mt)
            #pragma unroll
            for (int nt = 0; nt < 4; ++nt)
                sacc[mt][nt] = (f32x4){0.f, 0.f, 0.f, 0.f};
        {
            bf16x8 kf[4], qf[4];
            #pragma unroll
            for (int mt = 0; mt < 4; ++mt)
                kf[mt] = *(const bf16x8*)(kb + (mt * 16 + m16) * 64 + ((quad * 16) ^ swz2));
            #pragma unroll
            for (int nt = 0; nt < 4; ++nt)
                qf[nt] = *(const bf16x8*)(qb + (nt * 16 + m16) * 64 + ((quad * 16) ^ swz2));
            __builtin_amdgcn_s_setprio(1);
            #pragma unroll
            for (int mt = 0; mt < 4; ++mt)
                #pragma unroll
                for (int nt = 0; nt < 4; ++nt)
                    sacc[mt][nt] = __builtin_amdgcn_mfma_f32_16x16x32_bf16(
                        kf[mt], qf[nt], sacc[mt][nt], 0, 0, 0);
            __builtin_amdgcn_s_setprio(0);
        }

        // softmax per q-row (in-lane over 16 k + 2 quad shuffles); P -> LDS
        #pragma unroll
        for (int nt = 0; nt < 4; ++nt) {
            float e[4][4];
            float mx = -1e30f;
            #pragma unroll
            for (int mt = 0; mt < 4; ++mt)
                #pragma unroll
                for (int r = 0; r < 4; ++r) {
                    const int k = mt * 16 + quad * 4 + r;
                    float v = sacc[mt][nt][r] * scale;
                    if (k >= L_) v = -INFINITY;                  // pad cols: exact 0
                    else if ((mb[nt] >> k) & 1ull) v = -1000.0f; // ref semantics
                    e[mt][r] = v;
                    mx = fmaxf(mx, v);
                }
            mx = fmaxf(mx, __shfl_xor(mx, 16, 64));
            mx = fmaxf(mx, __shfl_xor(mx, 32, 64));
            float sum = 0.f;
            #pragma unroll
            for (int mt = 0; mt < 4; ++mt)
                #pragma unroll
                for (int r = 0; r < 4; ++r) {
                    const float ev = __expf(e[mt][r] - mx);
                    e[mt][r] = ev;
                    sum += ev;
                }
            sum += __shfl_xor(sum, 16, 64);
            sum += __shfl_xor(sum, 32, 64);
            const float inv = 1.0f / sum;
            const int prow = nt * 16 + m16;
            if (prow < L_) {
                #pragma unroll
                for (int mt = 0; mt < 4; ++mt) {
                    uint2 p;
                    p.x = cvtpk(e[mt][0] * inv, e[mt][1] * inv);
                    p.y = cvtpk(e[mt][2] * inv, e[mt][3] * inv);
                    *(uint2*)(qb + prow * 128 + ((mt * 32 + quad * 8) ^ swz3)) = p;
                }
            }
        }

        // O^T = V^T @ P^T : A from wave's V^T slot, B from P rows; K=64
        f32x4 oacc[2][4];
        #pragma unroll
        for (int mt2 = 0; mt2 < 2; ++mt2)
            #pragma unroll
            for (int nt = 0; nt < 4; ++nt)
                oacc[mt2][nt] = (f32x4){0.f, 0.f, 0.f, 0.f};
        #pragma unroll
        for (int kc = 0; kc < 2; ++kc) {
            bf16x8 vf[2], pf[4];
            #pragma unroll
            for (int mt2 = 0; mt2 < 2; ++mt2)
                vf[mt2] = *(const bf16x8*)(slot + (mt2 * 16 + m16) * 128 +
                                           ((kc * 64 + quad * 16) ^ swz3));
            #pragma unroll
            for (int nt = 0; nt < 4; ++nt)
                pf[nt] = *(const bf16x8*)(qb + (nt * 16 + m16) * 128 +
                                          ((kc * 64 + quad * 16) ^ swz3));
            __builtin_amdgcn_s_setprio(1);
            #pragma unroll
            for (int mt2 = 0; mt2 < 2; ++mt2)
                #pragma unroll
                for (int nt = 0; nt < 4; ++nt)
                    oacc[mt2][nt] = __builtin_amdgcn_mfma_f32_16x16x32_bf16(
                        vf[mt2], pf[nt], oacc[mt2][nt], 0, 0, 0);
            __builtin_amdgcn_s_setprio(0);
        }

        // O (A-layout, [49][32]) overlays P start
        #pragma unroll
        for (int nt = 0; nt < 4; ++nt) {
            const int prow = nt * 16 + m16;
            if (prow < L_) {
                #pragma unroll
                for (int mt2 = 0; mt2 < 2; ++mt2) {
                    uint2 o;
                    o.x = cvtpk(oacc[mt2][nt][0], oacc[mt2][nt][1]);
                    o.y = cvtpk(oacc[mt2][nt][2], oacc[mt2][nt][3]);
                    *(uint2*)(qb + prow * 64 +
                              ((mt2 * 32 + quad * 8) ^ (((prow >> 1) & 3) << 4))) = o;
                }
            }
        }

        // swap in head 2w+1's V^T (wave-private slot; DS ops in-order per wave)
        if (hh == 0) {
            #pragma unroll
            for (int nt2 = 0; nt2 < 2; ++nt2) {
                const int c = nt2 * 16 + m16;
                #pragma unroll
                for (int mt = 0; mt < 4; ++mt)
                    *(uint2*)(slot + c * 128 + ((mt * 32 + quad * 8) ^ swz3)) = vpk[nt2][mt];
            }
        }
    }

    __syncthreads();   // all heads' O ready

    // ---------------- out-proj: out = O @ Ww + bw, K=256 ----------------
    f32x4 cacc[4][3];
    #pragma unroll
    for (int mt = 0; mt < 4; ++mt)
        #pragma unroll
        for (int nt = 0; nt < 3; ++nt)
            cacc[mt][nt] = (f32x4){0.f, 0.f, 0.f, 0.f};
    #pragma unroll
    for (int kc = 0; kc < 8; ++kc) {
        char* Oh = qkR + kc * 6272;    // head kc's O
        bf16x8 af[4], bfw[3];
        #pragma unroll
        for (int mt = 0; mt < 4; ++mt)
            af[mt] = *(const bf16x8*)(Oh + (mt * 16 + m16) * 64 + ((quad * 16) ^ swz2));
        #pragma unroll
        for (int nt = 0; nt < 3; ++nt)
            bfw[nt] = *(const bf16x8*)&Wwt[(size_t)(wave * 48 + nt * 16 + m16) * PROJ_ +
                                           kc * 32 + quad * 8];
        __builtin_amdgcn_s_setprio(1);
        #pragma unroll
        for (int mt = 0; mt < 4; ++mt)
            #pragma unroll
            for (int nt = 0; nt < 3; ++nt)
                cacc[mt][nt] = __builtin_amdgcn_mfma_f32_16x16x32_bf16(
                    af[mt], bfw[nt], cacc[mt][nt], 0, 0, 0);
        __builtin_amdgcn_s_setprio(0);
    }
    #pragma unroll
    for (int nt = 0; nt < 3; ++nt) {
        const int col = wave * 48 + nt * 16 + m16;
        const float bias = bwb[col];
        #pragma unroll
        for (int mt = 0; mt < 4; ++mt)
            #pragma unroll
            for (int r = 0; r < 4; ++r) {
                const int i = mt * 16 + quad * 4 + r;
                if (i < L_)
                    out[((size_t)bw * L_ + i) * D_ + col] = cacc[mt][nt][r] + bias;
            }
    }
}

extern "C" void kernel_launch(void* const* d_in, const int* in_sizes, int n_in,
                              void* d_out, int out_size, void* d_ws, size_t ws_size,
                              hipStream_t stream) {
    const float* query = (const float*)d_in[0];
    const float* key_  = (const float*)d_in[1];
    const float* value = (const float*)d_in[2];
    const int*   mask  = (const int*)d_in[3];
    const float* Wq    = (const float*)d_in[4];
    const float* bq    = (const float*)d_in[5];
    const float* Wk    = (const float*)d_in[6];
    const float* bk    = (const float*)d_in[7];
    const float* Wv    = (const float*)d_in[8];
    const float* Ww    = (const float*)d_in[9];
    const float* bw    = (const float*)d_in[10];
    float* out = (float*)d_out;

    unsigned long long* mbits = (unsigned long long*)d_ws;     // 64*64 u64 = 32 KB
    short* Wqt = (short*)(mbits + 64 * 64);
    short* Wkt = Wqt + PROJ_ * D_;
    short* Wvt = Wkt + PROJ_ * D_;
    short* Wwt = Wvt + PROJ_ * D_;

    static bool attr_set = false;
    if (!attr_set) {
        (void)hipFuncSetAttribute(reinterpret_cast<const void*>(fused_kernel),
                                  hipFuncAttributeMaxDynamicSharedMemorySize, LDS_BYTES);
        attr_set = true;
    }

    prep_kernel<<<dim3(1216), 256, 0, stream>>>(Wq, Wk, Wv, Ww, mask,
                                                Wqt, Wkt, Wvt, Wwt, mbits);
    fused_kernel<<<dim3(BW_), 256, LDS_BYTES, stream>>>(
        query, key_, value, Wqt, Wkt, Wvt, bq, bk, mbits, Wwt, bw, out);
}